// Round 2
// baseline (322.962 us; speedup 1.0000x reference)
//
#include <hip/hip_runtime.h>
#include <hip/hip_bf16.h>

typedef __hip_bfloat16 bf16;
typedef __bf16 bfx8 __attribute__((ext_vector_type(8)));
typedef float f32x4 __attribute__((ext_vector_type(4)));

#define BM 128
#define BN 128
#define BK 32
#define LDSK 40   // padded LDS row stride (bf16): 80B -> 2-way bank aliasing only (free)

// ---------------------------------------------------------------------------
// de[e] = sum_n H[n][e]   (f32 input; partial rows per block + atomicAdd)
// grid: (E/256, N/128), block 256
__global__ void col_sum_kernel(const float* __restrict__ H, float* __restrict__ de, int E) {
    int e  = blockIdx.x * 256 + threadIdx.x;
    int n0 = blockIdx.y * 128;
    float s = 0.f;
    for (int n = 0; n < 128; n++) s += H[(size_t)(n0 + n) * E + e];
    atomicAdd(&de[e], s);
}

// dv_is[n] = rsqrt(sum_e H[n][e]*w[e] + eps)   one wave per row
__global__ void row_dv_kernel(const float* __restrict__ H, const float* __restrict__ w,
                              float* __restrict__ dv_is, int E) {
    int n    = blockIdx.x * 4 + (threadIdx.x >> 6);
    int lane = threadIdx.x & 63;
    const float* row = H + (size_t)n * E;
    float s = 0.f;
    for (int e = lane; e < E; e += 64) s += row[e] * w[e];
    for (int off = 32; off > 0; off >>= 1) s += __shfl_down(s, off);
    if (lane == 0) dv_is[n] = rsqrtf(s + 1e-8f);
}

// wsc[e] = w[e]/(de[e]+eps)
__global__ void wsc_kernel(const float* __restrict__ w, const float* __restrict__ de,
                           float* __restrict__ wsc, int E) {
    int e = blockIdx.x * 256 + threadIdx.x;
    if (e < E) wsc[e] = w[e] / (de[e] + 1e-8f);
}

// HT[e][n] = bf16(H[n][e])   64x64 LDS tiles, f32 in -> bf16 out
__global__ void transpose_kernel(const float* __restrict__ H, bf16* __restrict__ HT,
                                 int N, int E) {
    __shared__ bf16 tile[64][65];
    int eb = blockIdx.x * 64, nb = blockIdx.y * 64;
    for (int idx = threadIdx.x; idx < 4096; idx += 256) {
        int r = idx >> 6, c = idx & 63;
        tile[r][c] = __float2bfloat16(H[(size_t)(nb + r) * E + eb + c]);  // coalesced in e
    }
    __syncthreads();
    for (int idx = threadIdx.x; idx < 4096; idx += 256) {
        int r = idx >> 6, c = idx & 63;                  // r = local e, c = local n
        HT[(size_t)(eb + r) * N + nb + c] = tile[c][r];  // coalesced in n
    }
}

// ---------------------------------------------------------------------------
// B^T-form GEMM: C[row][col] = sum_k A[row][k] * Bt[col][k]
// Operands K-contiguous row-major. CONVA/CONVB: operand is f32, convert to bf16
// while staging to LDS. 128x128 tile, BK=32, 4 waves of 4x4 16x16x32 MFMAs.
// EPI 0: xs_t = bf16((acc + rvec[row]) * cvec[col])
// EPI 1: t_t  = bf16(acc * cvec[col])
// EPI 2: out[f32][(col>>8)*1048576 + row*256 + (col&255)] = acc * rvec[row]
template <int EPI, int CONVA, int CONVB>
__global__ __launch_bounds__(256) void gemm_bt(
    const void* __restrict__ Av, const void* __restrict__ Bv, int K,
    void* __restrict__ Cv, int ldc,
    const float* __restrict__ rvec, const float* __restrict__ cvec,
    long long aStride, long long bStride, long long cStride) {
    __shared__ __align__(16) bf16 As[BM * LDSK];
    __shared__ __align__(16) bf16 Bs[BN * LDSK];

    const float* Afp = (const float*)Av + (size_t)blockIdx.z * (size_t)aStride;
    const bf16*  Abp = (const bf16*)Av  + (size_t)blockIdx.z * (size_t)aStride;
    const float* Bfp = (const float*)Bv + (size_t)blockIdx.z * (size_t)bStride;
    const bf16*  Bbp = (const bf16*)Bv  + (size_t)blockIdx.z * (size_t)bStride;

    const int tid     = threadIdx.x;
    const int rowBase = blockIdx.y * BM;
    const int colBase = blockIdx.x * BN;
    const int wave = tid >> 6, lane = tid & 63;
    const int wr = (wave >> 1) * 64;
    const int wc = (wave & 1) * 64;
    const int lcol = lane & 15, quad = lane >> 4;

    f32x4 acc[4][4];
#pragma unroll
    for (int i = 0; i < 4; i++)
#pragma unroll
        for (int j = 0; j < 4; j++) acc[i][j] = (f32x4){0.f, 0.f, 0.f, 0.f};

    for (int k0 = 0; k0 < K; k0 += BK) {
        // stage 128x32 tiles: 512 chunks of 8 elems, 2 per thread per matrix
#pragma unroll
        for (int c = 0; c < 2; c++) {
            int ch = tid + c * 256;
            int r = ch >> 2, kc = (ch & 3) << 3;
            size_t off = (size_t)(rowBase + r) * K + k0 + kc;
            if (CONVA) {
                f32x4 p0 = *(const f32x4*)&Afp[off];
                f32x4 p1 = *(const f32x4*)&Afp[off + 4];
                bfx8 v;
#pragma unroll
                for (int t = 0; t < 4; t++) { v[t] = (__bf16)p0[t]; v[4 + t] = (__bf16)p1[t]; }
                *(bfx8*)&As[r * LDSK + kc] = v;
            } else {
                *(bfx8*)&As[r * LDSK + kc] = *(const bfx8*)&Abp[off];
            }
            size_t boff = (size_t)(colBase + r) * K + k0 + kc;
            if (CONVB) {
                f32x4 p0 = *(const f32x4*)&Bfp[boff];
                f32x4 p1 = *(const f32x4*)&Bfp[boff + 4];
                bfx8 v;
#pragma unroll
                for (int t = 0; t < 4; t++) { v[t] = (__bf16)p0[t]; v[4 + t] = (__bf16)p1[t]; }
                *(bfx8*)&Bs[r * LDSK + kc] = v;
            } else {
                *(bfx8*)&Bs[r * LDSK + kc] = *(const bfx8*)&Bbp[boff];
            }
        }
        __syncthreads();

        bfx8 af[4], bfr[4];
#pragma unroll
        for (int i = 0; i < 4; i++)
            af[i] = *(const bfx8*)&As[(wr + i * 16 + lcol) * LDSK + quad * 8];
#pragma unroll
        for (int j = 0; j < 4; j++)
            bfr[j] = *(const bfx8*)&Bs[(wc + j * 16 + lcol) * LDSK + quad * 8];
#pragma unroll
        for (int i = 0; i < 4; i++)
#pragma unroll
            for (int j = 0; j < 4; j++)
                acc[i][j] = __builtin_amdgcn_mfma_f32_16x16x32_bf16(af[i], bfr[j], acc[i][j], 0, 0, 0);
        __syncthreads();
    }

    // epilogue: C/D layout col=lane&15, row=quad*4+reg  [verified m89/m91]
    bf16*  Cb = (bf16*)Cv  + (size_t)blockIdx.z * (size_t)cStride;
    float* Cf = (float*)Cv;
#pragma unroll
    for (int i = 0; i < 4; i++) {
#pragma unroll
        for (int j = 0; j < 4; j++) {
#pragma unroll
            for (int r = 0; r < 4; r++) {
                int grow = rowBase + wr + i * 16 + quad * 4 + r;
                int gcol = colBase + wc + j * 16 + lcol;
                float v = acc[i][j][r];
                if (EPI == 0) {
                    v = (v + rvec[grow]) * cvec[gcol];
                    Cb[(size_t)grow * ldc + gcol] = __float2bfloat16(v);
                } else if (EPI == 1) {
                    v = v * cvec[gcol];
                    Cb[(size_t)grow * ldc + gcol] = __float2bfloat16(v);
                } else {
                    v = v * rvec[grow];
                    Cf[(size_t)(gcol >> 8) * 1048576 + (size_t)grow * 256 + (gcol & 255)] = v;
                }
            }
        }
    }
}

// ---------------------------------------------------------------------------
extern "C" void kernel_launch(void* const* d_in, const int* in_sizes, int n_in,
                              void* d_out, int out_size, void* d_ws, size_t ws_size,
                              hipStream_t stream) {
    const float* x    = (const float*)d_in[0];  // [8,4096,256] f32
    const float* ew   = (const float*)d_in[1];  // [2048]       f32
    const float* H    = (const float*)d_in[2];  // [4096,2048]  f32
    const float* W    = (const float*)d_in[3];  // [256,256]    f32 (W[o][d])
    const float* bias = (const float*)d_in[4];  // [256]        f32
    float* out = (float*)d_out;                 // [8,4096,256] f32

    const int N = 4096, E = 2048;

    char* ws = (char*)d_ws;
    float* de    = (float*)(ws);               // 2048 f32
    float* dv_is = (float*)(ws + 8192);        // 4096 f32
    float* wsc   = (float*)(ws + 24576);       // 2048 f32
    bf16*  HT    = (bf16*)(ws + 65536);                    // [E][N]       16 MB
    bf16*  xs_t  = (bf16*)(ws + 65536 + 16777216);         // [2048][4096] 16 MB
    bf16*  t_t   = (bf16*)(ws + 65536 + 2 * 16777216);     // [2048][2048]  8 MB

    hipMemsetAsync(de, 0, E * sizeof(float), stream);
    col_sum_kernel<<<dim3(E / 256, N / 128), 256, 0, stream>>>(H, de, E);
    row_dv_kernel<<<dim3(N / 4), 256, 0, stream>>>(H, ew, dv_is, E);
    wsc_kernel<<<dim3(E / 256), 256, 0, stream>>>(ew, de, wsc, E);
    transpose_kernel<<<dim3(E / 64, N / 64), 256, 0, stream>>>(H, HT, N, E);

    // K3: xs_t[b*256+o][n] = dv_is[n]*(sum_d W[o][d]*x[b][n][d] + bias[o])
    gemm_bt<0, 1, 1><<<dim3(4096 / BN, 256 / BM, 8), 256, 0, stream>>>(
        W, x, 256, xs_t, 4096, bias, dv_is,
        0LL, 1048576LL /* x batch stride, elems */, 1048576LL /* xs_t batch stride */);

    // K4: t_t[c][e] = wsc[e] * sum_n xs_t[c][n] * HT[e][n]
    gemm_bt<1, 0, 0><<<dim3(2048 / BN, 2048 / BM, 1), 256, 0, stream>>>(
        xs_t, HT, 4096, t_t, 2048, nullptr, wsc, 0LL, 0LL, 0LL);

    // K5: out[b][n][o] = dv_is[n] * sum_e H[n][e] * t_t[b*256+o][e]
    gemm_bt<2, 1, 0><<<dim3(2048 / BN, 4096 / BM, 1), 256, 0, stream>>>(
        H, t_t, 2048, out, 0, dv_is, nullptr, 0LL, 0LL, 0LL);
}

// Round 3
// 270.604 us; speedup vs baseline: 1.1935x; 1.1935x over previous
//
#include <hip/hip_runtime.h>
#include <hip/hip_bf16.h>

typedef __hip_bfloat16 bf16;
typedef __bf16 bfx8 __attribute__((ext_vector_type(8)));
typedef float f32x4 __attribute__((ext_vector_type(4)));

#define BM 128
#define BN 128
#define BK 32

typedef __attribute__((address_space(3))) void lds_void_t;
typedef const __attribute__((address_space(1))) void gbl_void_t;

// ---------------------------------------------------------------------------
// Fused prep: HT[e][n] = bf16(H[n][e]); de[e] += colsum; dvr[n] += row·w
// H is binary (0/1) so bf16 rounding is EXACT for the degree sums.
// grid: (E/64, N/64), block 256. tid = g*64 + c (g = wave id 0..3).
__global__ void prep_kernel(const float* __restrict__ H, const float* __restrict__ w,
                            bf16* __restrict__ HT, float* __restrict__ de,
                            float* __restrict__ dvr, int N, int E) {
    __shared__ bf16 tile[64][65];
    __shared__ float cred[4][64];
    __shared__ float rred[4][64];
    int eb = blockIdx.x * 64, nb = blockIdx.y * 64;
    int tid = threadIdx.x;
    int c = tid & 63, g = tid >> 6;

    float cs = 0.f;
#pragma unroll
    for (int k = 0; k < 16; k++) {
        int r = g + (k << 2);                       // local n row
        float v = H[(size_t)(nb + r) * E + eb + c]; // coalesced in e
        tile[r][c] = __float2bfloat16(v);
        cs += v;
    }
    cred[g][c] = cs;
    __syncthreads();

    if (g == 0) {  // column (hyperedge) degree
        float s = cred[0][c] + cred[1][c] + cred[2][c] + cred[3][c];
        atomicAdd(&de[eb + c], s);
    }
    // row dot with w: thread covers row c, cols g+4k (tile values exact)
    float rs = 0.f;
#pragma unroll
    for (int k = 0; k < 16; k++) {
        int cc = g + (k << 2);
        rs += __bfloat162float(tile[c][cc]) * w[eb + cc];
    }
    rred[g][c] = rs;
    __syncthreads();
    if (g == 1) {
        float s = rred[0][c] + rred[1][c] + rred[2][c] + rred[3][c];
        atomicAdd(&dvr[nb + c], s);
    }
    // transposed store: local e = r, local n = c  (coalesced in n)
#pragma unroll
    for (int k = 0; k < 16; k++) {
        int r = g + (k << 2);
        HT[(size_t)(eb + r) * N + nb + c] = tile[c][r];
    }
}

// dv_is[n] = rsqrt(dvr[n]+eps); wsc[e] = w[e]/(de[e]+eps)
__global__ void finalize_kernel(const float* __restrict__ dvr, const float* __restrict__ de,
                                const float* __restrict__ w, float* __restrict__ dv_is,
                                float* __restrict__ wsc, int N, int E) {
    int i = blockIdx.x * 256 + threadIdx.x;
    if (i < N) dv_is[i] = rsqrtf(dvr[i] + 1e-8f);
    if (i < E) wsc[i] = w[i] / (de[i] + 1e-8f);
}

// Hb = bf16(H), row-major (exact: H binary). 8 elems/thread.
__global__ void h2b_kernel(const float* __restrict__ H, bf16* __restrict__ Hb) {
    size_t i = ((size_t)blockIdx.x * 256 + threadIdx.x) * 8;
    f32x4 p0 = *(const f32x4*)&H[i];
    f32x4 p1 = *(const f32x4*)&H[i + 4];
    bfx8 v;
#pragma unroll
    for (int t = 0; t < 4; t++) { v[t] = (__bf16)p0[t]; v[4 + t] = (__bf16)p1[t]; }
    *(bfx8*)&Hb[i] = v;
}

// ---------------------------------------------------------------------------
// Async B^T-form GEMM (m97 structure): pure-bf16 operands, global_load_lds
// width=16 staging into UNPADDED stride-32 LDS (wave-uniform base + lane*16).
// C[row][col] = sum_k A[row][k]*Bt[col][k]
// EPI 1: t_t[bf16] = acc * cvec[col]
// EPI 2: out[f32][(col>>8)*1048576 + row*256 + (col&255)] = acc * rvec[row]
template <int EPI>
__global__ __launch_bounds__(256) void gemm_bt_async(
    const bf16* __restrict__ A, const bf16* __restrict__ Bt, int K,
    void* __restrict__ Cv, int ldc,
    const float* __restrict__ rvec, const float* __restrict__ cvec) {
    __shared__ __align__(16) bf16 As[BM * 32];
    __shared__ __align__(16) bf16 Bs[BN * 32];

    const int tid     = threadIdx.x;
    const int rowBase = blockIdx.y * BM;
    const int colBase = blockIdx.x * BN;
    const int wave = tid >> 6, lane = tid & 63;
    const int wr = (wave >> 1) * 64;
    const int wc = (wave & 1) * 64;
    const int lcol = lane & 15, quad = lane >> 4;

    // staging map: chunk ch in [0,512), LDS byte = ch*16 (lane-contiguous per wave)
    const int sr = tid >> 2, skc = (tid & 3) << 3;   // chunks (sr,skc) and (sr+64,skc)
    const bf16* a0 = &A[(size_t)(rowBase + sr) * K + skc];
    const bf16* a1 = a0 + (size_t)64 * K;
    const bf16* b0 = &Bt[(size_t)(colBase + sr) * K + skc];
    const bf16* b1 = b0 + (size_t)64 * K;
    bf16* asd0 = &As[sr * 32 + skc];
    bf16* asd1 = &As[(sr + 64) * 32 + skc];
    bf16* bsd0 = &Bs[sr * 32 + skc];
    bf16* bsd1 = &Bs[(sr + 64) * 32 + skc];

    f32x4 acc[4][4];
#pragma unroll
    for (int i = 0; i < 4; i++)
#pragma unroll
        for (int j = 0; j < 4; j++) acc[i][j] = (f32x4){0.f, 0.f, 0.f, 0.f};

    for (int k0 = 0; k0 < K; k0 += BK) {
        __builtin_amdgcn_global_load_lds((gbl_void_t*)(a0 + k0), (lds_void_t*)asd0, 16, 0, 0);
        __builtin_amdgcn_global_load_lds((gbl_void_t*)(a1 + k0), (lds_void_t*)asd1, 16, 0, 0);
        __builtin_amdgcn_global_load_lds((gbl_void_t*)(b0 + k0), (lds_void_t*)bsd0, 16, 0, 0);
        __builtin_amdgcn_global_load_lds((gbl_void_t*)(b1 + k0), (lds_void_t*)bsd1, 16, 0, 0);
        __syncthreads();

        bfx8 af[4], bfr[4];
#pragma unroll
        for (int i = 0; i < 4; i++)
            af[i] = *(const bfx8*)&As[(wr + i * 16 + lcol) * 32 + quad * 8];
#pragma unroll
        for (int j = 0; j < 4; j++)
            bfr[j] = *(const bfx8*)&Bs[(wc + j * 16 + lcol) * 32 + quad * 8];
#pragma unroll
        for (int i = 0; i < 4; i++)
#pragma unroll
            for (int j = 0; j < 4; j++)
                acc[i][j] = __builtin_amdgcn_mfma_f32_16x16x32_bf16(af[i], bfr[j], acc[i][j], 0, 0, 0);
        __syncthreads();
    }

    // C/D layout: col=lane&15, row=quad*4+reg  [verified m89/m91]
    bf16*  Cb = (bf16*)Cv;
    float* Cf = (float*)Cv;
#pragma unroll
    for (int i = 0; i < 4; i++) {
#pragma unroll
        for (int j = 0; j < 4; j++) {
#pragma unroll
            for (int r = 0; r < 4; r++) {
                int grow = rowBase + wr + i * 16 + quad * 4 + r;
                int gcol = colBase + wc + j * 16 + lcol;
                float v = acc[i][j][r];
                if (EPI == 1) {
                    Cb[(size_t)grow * ldc + gcol] = __float2bfloat16(v * cvec[gcol]);
                } else {
                    Cf[(size_t)(gcol >> 8) * 1048576 + (size_t)grow * 256 + (gcol & 255)] =
                        v * rvec[grow];
                }
            }
        }
    }
}

// ---------------------------------------------------------------------------
// Sync-staged conv GEMM (K3 only): both operands f32, convert while staging.
// xs_t[bf16] = (acc + rvec[row]) * cvec[col]
__global__ __launch_bounds__(256) void gemm_bt_conv(
    const float* __restrict__ A, const float* __restrict__ B, int K,
    bf16* __restrict__ C, int ldc,
    const float* __restrict__ rvec, const float* __restrict__ cvec,
    long long bStride, long long cStride) {
    __shared__ __align__(16) bf16 As[BM * 40];
    __shared__ __align__(16) bf16 Bs[BN * 40];

    const float* Bp = B + (size_t)blockIdx.z * (size_t)bStride;
    bf16*        Cp = C + (size_t)blockIdx.z * (size_t)cStride;

    const int tid     = threadIdx.x;
    const int rowBase = blockIdx.y * BM;
    const int colBase = blockIdx.x * BN;
    const int wave = tid >> 6, lane = tid & 63;
    const int wr = (wave >> 1) * 64;
    const int wc = (wave & 1) * 64;
    const int lcol = lane & 15, quad = lane >> 4;

    f32x4 acc[4][4];
#pragma unroll
    for (int i = 0; i < 4; i++)
#pragma unroll
        for (int j = 0; j < 4; j++) acc[i][j] = (f32x4){0.f, 0.f, 0.f, 0.f};

    for (int k0 = 0; k0 < K; k0 += BK) {
#pragma unroll
        for (int c = 0; c < 2; c++) {
            int ch = tid + c * 256;
            int r = ch >> 2, kc = (ch & 3) << 3;
            size_t aoff = (size_t)(rowBase + r) * K + k0 + kc;
            size_t boff = (size_t)(colBase + r) * K + k0 + kc;
            f32x4 p0 = *(const f32x4*)&A[aoff];
            f32x4 p1 = *(const f32x4*)&A[aoff + 4];
            bfx8 va;
#pragma unroll
            for (int t = 0; t < 4; t++) { va[t] = (__bf16)p0[t]; va[4 + t] = (__bf16)p1[t]; }
            *(bfx8*)&As[r * 40 + kc] = va;
            f32x4 q0 = *(const f32x4*)&Bp[boff];
            f32x4 q1 = *(const f32x4*)&Bp[boff + 4];
            bfx8 vb;
#pragma unroll
            for (int t = 0; t < 4; t++) { vb[t] = (__bf16)q0[t]; vb[4 + t] = (__bf16)q1[t]; }
            *(bfx8*)&Bs[r * 40 + kc] = vb;
        }
        __syncthreads();

        bfx8 af[4], bfr[4];
#pragma unroll
        for (int i = 0; i < 4; i++)
            af[i] = *(const bfx8*)&As[(wr + i * 16 + lcol) * 40 + quad * 8];
#pragma unroll
        for (int j = 0; j < 4; j++)
            bfr[j] = *(const bfx8*)&Bs[(wc + j * 16 + lcol) * 40 + quad * 8];
#pragma unroll
        for (int i = 0; i < 4; i++)
#pragma unroll
            for (int j = 0; j < 4; j++)
                acc[i][j] = __builtin_amdgcn_mfma_f32_16x16x32_bf16(af[i], bfr[j], acc[i][j], 0, 0, 0);
        __syncthreads();
    }

#pragma unroll
    for (int i = 0; i < 4; i++) {
#pragma unroll
        for (int j = 0; j < 4; j++) {
#pragma unroll
            for (int r = 0; r < 4; r++) {
                int grow = rowBase + wr + i * 16 + quad * 4 + r;
                int gcol = colBase + wc + j * 16 + lcol;
                float v = (acc[i][j][r] + rvec[grow]) * cvec[gcol];
                Cp[(size_t)grow * ldc + gcol] = __float2bfloat16(v);
            }
        }
    }
}

// ---------------------------------------------------------------------------
extern "C" void kernel_launch(void* const* d_in, const int* in_sizes, int n_in,
                              void* d_out, int out_size, void* d_ws, size_t ws_size,
                              hipStream_t stream) {
    const float* x    = (const float*)d_in[0];  // [8,4096,256]
    const float* ew   = (const float*)d_in[1];  // [2048]
    const float* H    = (const float*)d_in[2];  // [4096,2048]
    const float* W    = (const float*)d_in[3];  // [256,256]
    const float* bias = (const float*)d_in[4];  // [256]
    float* out = (float*)d_out;                 // [8,4096,256]

    const int N = 4096, E = 2048;

    char* ws = (char*)d_ws;
    float* de    = (float*)(ws);               // 2048 f32
    float* dvr   = (float*)(ws + 8192);        // 4096 f32
    float* dv_is = (float*)(ws + 24576);       // 4096 f32
    float* wsc   = (float*)(ws + 40960);       // 2048 f32
    bf16*  HT    = (bf16*)(ws + 65536);                // [E][N] 16 MB; reused as Hb [N][E] after K4
    bf16*  xs_t  = (bf16*)(ws + 65536 + 16777216);     // [2048][4096] 16 MB
    bf16*  t_t   = (bf16*)(ws + 65536 + 2 * 16777216); // [2048][2048]  8 MB

    hipMemsetAsync(ws, 0, 24576, stream);  // de + dvr

    // prep: HT + degrees in one pass over H
    prep_kernel<<<dim3(E / 64, N / 64), 256, 0, stream>>>(H, ew, HT, de, dvr, N, E);
    finalize_kernel<<<dim3(16), 256, 0, stream>>>(dvr, de, ew, dv_is, wsc, N, E);

    // K3: xs_t[b*256+o][n] = dv_is[n]*(sum_d W[o][d]*x[b][n][d] + bias[o])
    gemm_bt_conv<<<dim3(4096 / BN, 256 / BM, 8), 256, 0, stream>>>(
        W, x, 256, xs_t, 4096, bias, dv_is, 1048576LL, 1048576LL);

    // K4: t_t[c][e] = wsc[e] * sum_n xs_t[c][n] * HT[e][n]
    gemm_bt_async<1><<<dim3(2048 / BN, 2048 / BM, 1), 256, 0, stream>>>(
        xs_t, HT, 4096, t_t, 2048, nullptr, wsc);

    // HT dead -> overwrite with Hb = bf16(H) row-major (exact, H binary)
    bf16* Hb = HT;
    h2b_kernel<<<dim3((N * E / 8) / 256), 256, 0, stream>>>(H, Hb);

    // K5: out[b][n][o] = dv_is[n] * sum_e Hb[n][e] * t_t[b*256+o][e]
    gemm_bt_async<2><<<dim3(2048 / BN, 4096 / BM, 1), 256, 0, stream>>>(
        Hb, t_t, 2048, out, 0, dv_is, nullptr);
}